// Round 4
// baseline (336.385 us; speedup 1.0000x reference)
//
#include <hip/hip_runtime.h>

#define DD 300
#define KK 50
#define BB 32
#define SS 8192
#define NN 128
#define LL 64
#define NSEG (BB * NN)        // 4096

#define WPB_YU 8              // segments (waves) per k_yu block
#define NT_YU  (WPB_YU * 64)  // 512
#define WPB_R  4              // waves (=segments) per k_rest block
#define NT_R   (WPB_R * 64)   // 256

__device__ __forceinline__ float wave_sum(float v) {
    #pragma unroll
    for (int m = 32; m; m >>= 1) v += __shfl_xor(v, m, 64);
    return v;
}
__device__ __forceinline__ float wave_max(float v) {
    #pragma unroll
    for (int m = 32; m; m >>= 1) v = fmaxf(v, __shfl_xor(v, m, 64));
    return v;
}
__device__ __forceinline__ float dot4(float4 a, float4 b) {
    return a.x * b.x + a.y * b.y + a.z * b.z + a.w * b.w;
}

// ================= K1: y (wave-per-segment) + u (block-cooperative GEMM) =================
__global__ __launch_bounds__(NT_YU) void k_yu(
    const float* __restrict__ emb,
    const float* __restrict__ M_w,        // [D,D]
    const int*   __restrict__ tokens,
    const int*   __restrict__ seg_starts,
    const int*   __restrict__ seg_lens,
    float* __restrict__ out_y,            // [NSEG, D]
    float* __restrict__ u_ws)             // [NSEG, D]
{
    __shared__ float y_s[WPB_YU][DD];     // 9.6 KB

    const int tid  = threadIdx.x;
    const int wave = tid >> 6;
    const int lane = tid & 63;
    const int seg  = blockIdx.x * WPB_YU + wave;
    const int b    = seg >> 7;            // N = 128
    const int start = seg_starts[seg];
    const int len   = seg_lens[seg];

    const int tok = tokens[b * SS + start + lane];   // one token per lane

    // ---- y: masked mean, float4 chunks (d = 4*lane [+256]) ----
    float4 a0 = {0.f, 0.f, 0.f, 0.f};
    float4 a1 = {0.f, 0.f, 0.f, 0.f};
    #pragma unroll 4
    for (int l = 0; l < len; ++l) {
        const int t = __shfl(tok, l);
        const float4* row4 = (const float4*)(emb + (size_t)t * DD);
        const float4 r0 = row4[lane];
        a0.x += r0.x; a0.y += r0.y; a0.z += r0.z; a0.w += r0.w;
        if (lane < 11) {
            const float4 r1 = row4[64 + lane];
            a1.x += r1.x; a1.y += r1.y; a1.z += r1.z; a1.w += r1.w;
        }
    }
    const float inv = 1.f / (float)len;
    a0.x *= inv; a0.y *= inv; a0.z *= inv; a0.w *= inv;
    a1.x *= inv; a1.y *= inv; a1.z *= inv; a1.w *= inv;

    {
        float4* yo = (float4*)(out_y + (size_t)seg * DD);
        yo[lane] = a0;
        if (lane < 11) yo[64 + lane] = a1;
        float4* ys = (float4*)(&y_s[wave][0]);
        ys[lane] = a0;
        if (lane < 11) ys[64 + lane] = a1;
    }
    __syncthreads();

    // ---- u[r][d] = sum_e y[r][e] * M_w[e][d], thread-owns-d, 8 segs in registers ----
    if (tid < DD) {
        float acc[WPB_YU];
        #pragma unroll
        for (int r = 0; r < WPB_YU; ++r) acc[r] = 0.f;
        #pragma unroll 2
        for (int e = 0; e < DD; ++e) {
            const float m = M_w[(size_t)e * DD + tid];
            #pragma unroll
            for (int r = 0; r < WPB_YU; ++r) acc[r] += m * y_s[r][e];   // LDS broadcast
        }
        #pragma unroll
        for (int r = 0; r < WPB_YU; ++r)
            u_ws[(size_t)(blockIdx.x * WPB_YU + r) * DD + tid] = acc[r];
    }
}

// ================= K2: wave-per-segment, zero barriers =================
__global__ __launch_bounds__(NT_R) void k_rest(
    const float* __restrict__ emb,
    const float* __restrict__ W_w,        // [K,D]
    const float* __restrict__ T_w,        // [D,K]
    const int*   __restrict__ tokens,
    const int*   __restrict__ seg_starts,
    const int*   __restrict__ seg_lens,
    const float* __restrict__ u_ws,       // [NSEG, D]
    float* __restrict__ out_z,
    float* __restrict__ out_p,
    float* __restrict__ out_r)
{
    const int tid  = threadIdx.x;
    const int wave = tid >> 6;
    const int lane = tid & 63;
    const int seg  = blockIdx.x * WPB_R + wave;
    const int b    = seg >> 7;
    const int start = seg_starts[seg];
    const int len   = seg_lens[seg];

    const int tok = tokens[b * SS + start + lane];

    // u chunks (d = 4*lane [+256])
    float4 u0, u1 = {0.f, 0.f, 0.f, 0.f};
    {
        const float4* uu = (const float4*)(u_ws + (size_t)seg * DD);
        u0 = uu[lane];
        if (lane < 11) u1 = uu[64 + lane];
    }

    // ---- esc per row: wave-dot, result deposited in lane l ----
    float esc = -INFINITY;
    #pragma unroll 2
    for (int l = 0; l < len; ++l) {
        const int t = __shfl(tok, l);
        const float4* row4 = (const float4*)(emb + (size_t)t * DD);
        float d = dot4(row4[lane], u0);
        if (lane < 11) d += dot4(row4[64 + lane], u1);
        d = wave_sum(d);
        esc = (lane == l) ? d : esc;
    }

    // ---- softmax over rows (pure shuffles) ----
    const float mx = wave_max(esc);
    const float ex = (lane < len) ? __expf(esc - mx) : 0.f;
    const float sm = wave_sum(ex);
    const float alpha = ex / sm;          // alpha for row `lane`

    // ---- z = sum_l alpha_l * row_l (rows re-read, L2-hot) ----
    float4 z0 = {0.f, 0.f, 0.f, 0.f};
    float4 z1 = {0.f, 0.f, 0.f, 0.f};
    #pragma unroll 2
    for (int l = 0; l < len; ++l) {
        const int t = __shfl(tok, l);
        const float a = __shfl(alpha, l);
        const float4* row4 = (const float4*)(emb + (size_t)t * DD);
        const float4 r0 = row4[lane];
        z0.x += a * r0.x; z0.y += a * r0.y; z0.z += a * r0.z; z0.w += a * r0.w;
        if (lane < 11) {
            const float4 r1 = row4[64 + lane];
            z1.x += a * r1.x; z1.y += a * r1.y; z1.z += a * r1.z; z1.w += a * r1.w;
        }
    }
    {
        float4* zo = (float4*)(out_z + (size_t)seg * DD);
        zo[lane] = z0;
        if (lane < 11) zo[64 + lane] = z1;
    }

    // ---- topic scores: 50 wave-dots vs register-resident z ----
    float sc = -INFINITY;
    #pragma unroll 2
    for (int k = 0; k < KK; ++k) {
        const float4* w4 = (const float4*)(W_w + (size_t)k * DD);
        float d = dot4(w4[lane], z0);
        if (lane < 11) d += dot4(w4[64 + lane], z1);
        d = wave_sum(d);
        sc = (lane == k) ? d : sc;
    }
    const float mxk = wave_max(sc);
    const float ek  = (lane < KK) ? __expf(sc - mxk) : 0.f;
    const float smk = wave_sum(ek);
    const float p   = ek / smk;           // p for topic `lane`
    if (lane < KK) out_p[(size_t)seg * KK + lane] = p;

    // ---- r[d] = sum_k p_k * T_w[d,k]  (d = lane + 64c mapping) ----
    float r0 = 0.f, r1 = 0.f, r2 = 0.f, r3 = 0.f, r4 = 0.f;
    #pragma unroll 2
    for (int k = 0; k < KK; ++k) {
        const float pk = __shfl(p, k);
        r0 += pk * T_w[(size_t)(lane      ) * KK + k];
        r1 += pk * T_w[(size_t)(lane +  64) * KK + k];
        r2 += pk * T_w[(size_t)(lane + 128) * KK + k];
        r3 += pk * T_w[(size_t)(lane + 192) * KK + k];
        if (lane < 44) r4 += pk * T_w[(size_t)(lane + 256) * KK + k];
    }
    {
        float* ro = out_r + (size_t)seg * DD;
        ro[lane]       = r0;
        ro[lane +  64] = r1;
        ro[lane + 128] = r2;
        ro[lane + 192] = r3;
        if (lane < 44) ro[lane + 256] = r4;
    }
}

extern "C" void kernel_launch(void* const* d_in, const int* in_sizes, int n_in,
                              void* d_out, int out_size, void* d_ws, size_t ws_size,
                              hipStream_t stream) {
    const float* emb        = (const float*)d_in[0];
    const float* M_w        = (const float*)d_in[1];
    const float* W_w        = (const float*)d_in[2];
    const float* T_w        = (const float*)d_in[3];
    const int*   tokens     = (const int*)d_in[4];
    const int*   seg_starts = (const int*)d_in[5];
    const int*   seg_lens   = (const int*)d_in[6];

    float* out   = (float*)d_out;
    float* out_y = out;                                    // [NSEG*D]
    float* out_z = out + (size_t)NSEG * DD;                // [NSEG*D]
    float* out_p = out + (size_t)2 * NSEG * DD;            // [NSEG*K]
    float* out_r = out + (size_t)2 * NSEG * DD + (size_t)NSEG * KK;

    float* u_ws = (float*)d_ws;                            // [NSEG*D] = 4.9 MB

    hipLaunchKernelGGL(k_yu, dim3(NSEG / WPB_YU), dim3(NT_YU), 0, stream,
                       emb, M_w, tokens, seg_starts, seg_lens, out_y, u_ws);
    hipLaunchKernelGGL(k_rest, dim3(NSEG / WPB_R), dim3(NT_R), 0, stream,
                       emb, W_w, T_w, tokens, seg_starts, seg_lens,
                       u_ws, out_z, out_p, out_r);
}

// Round 5
// 182.102 us; speedup vs baseline: 1.8472x; 1.8472x over previous
//
#include <hip/hip_runtime.h>

#define DD 300
#define KK 50
#define BB 32
#define SS 8192
#define NN 128
#define LL 64
#define NSEG (BB * NN)   // 4096
#define NW 5             // waves per block (k_y / k_rest)
#define NT 320           // threads per block
#define NJ 13            // rows per wave = ceil(64/5)
#define NC 5             // 64-lane dword chunks per row (300 = 4*64 + 44)
#define TM 8             // segments per k_u block

__device__ __forceinline__ float wave_sum(float v) {
    #pragma unroll
    for (int m = 32; m; m >>= 1) v += __shfl_xor(v, m, 64);
    return v;
}
__device__ __forceinline__ float wave_max(float v) {
    #pragma unroll
    for (int m = 32; m; m >>= 1) v = fmaxf(v, __shfl_xor(v, m, 64));
    return v;
}

// ============ K1: y = masked mean. Branch-free gather: 65 independent loads, then masked sum ============
__global__ __launch_bounds__(NT) void k_y(
    const float* __restrict__ emb,
    const int*   __restrict__ tokens,
    const int*   __restrict__ seg_starts,
    const int*   __restrict__ seg_lens,
    float* __restrict__ out_y)
{
    __shared__ int   tok_s[LL];
    __shared__ float part[NW][NT];

    const int tid  = threadIdx.x;
    const int wave = tid >> 6;
    const int lane = tid & 63;
    const int seg  = blockIdx.x;
    const int b    = seg >> 7;                 // N = 128
    const int start = seg_starts[seg];
    const int len   = seg_lens[seg];

    if (tid < LL) tok_s[tid] = tokens[b * SS + start + tid];
    __syncthreads();

    // ---- pure-load phase: unconditional, clamped row index ----
    float rr[NJ][NC];
    #pragma unroll
    for (int j = 0; j < NJ; ++j) {
        const int l  = wave + j * NW;
        const int lc = (l < len) ? l : (len - 1);
        const float* row = emb + (size_t)tok_s[lc] * DD;
        rr[j][0] = row[lane];
        rr[j][1] = row[lane + 64];
        rr[j][2] = row[lane + 128];
        rr[j][3] = row[lane + 192];
        rr[j][4] = (lane < 44) ? row[lane + 256] : 0.f;
    }
    // ---- masked accumulate ----
    float acc[NC] = {0.f, 0.f, 0.f, 0.f, 0.f};
    #pragma unroll
    for (int j = 0; j < NJ; ++j) {
        const int l = wave + j * NW;
        const float m = (l < len) ? 1.f : 0.f;
        #pragma unroll
        for (int c = 0; c < NC; ++c) acc[c] += m * rr[j][c];
    }
    #pragma unroll
    for (int c = 0; c < NC; ++c) part[wave][lane + 64 * c] = acc[c];
    __syncthreads();

    if (tid < DD) {
        const float s = part[0][tid] + part[1][tid] + part[2][tid] + part[3][tid] + part[4][tid];
        out_y[(size_t)seg * DD + tid] = s / (float)len;
    }
}

// ============ K2: u = y @ M_w. y via wave-uniform (scalar) loads, TM=8 segs/block ============
__global__ __launch_bounds__(NT) void k_u(
    const float* __restrict__ y,      // [NSEG, D]
    const float* __restrict__ M_w,    // [D, D]
    float* __restrict__ u)            // [NSEG, D]
{
    const int tid  = threadIdx.x;
    const int row0 = blockIdx.x * TM;
    if (tid >= DD) return;            // no barriers below

    float acc[TM];
    #pragma unroll
    for (int r = 0; r < TM; ++r) acc[r] = 0.f;

    #pragma unroll 5
    for (int e = 0; e < DD; ++e) {
        const float m = M_w[(size_t)e * DD + tid];          // coalesced vector load
        #pragma unroll
        for (int r = 0; r < TM; ++r)
            acc[r] += m * y[(size_t)(row0 + r) * DD + e];   // uniform addr -> s_load
    }
    #pragma unroll
    for (int r = 0; r < TM; ++r)
        u[(size_t)(row0 + r) * DD + tid] = acc[r];
}

// ============ K3: esc / softmax / z / p / r — rows register-resident, branch-free gather ============
__global__ __launch_bounds__(NT) void k_rest(
    const float* __restrict__ emb,
    const float* __restrict__ W_w,    // [K, D]
    const float* __restrict__ T_w,    // [D, K]
    const int*   __restrict__ tokens,
    const int*   __restrict__ seg_starts,
    const int*   __restrict__ seg_lens,
    const float* __restrict__ u_ws,   // [NSEG, D]
    float* __restrict__ out_z,
    float* __restrict__ out_p,
    float* __restrict__ out_r)
{
    __shared__ int   tok_s[LL];
    __shared__ float a_s[LL + 1];     // alpha; a_s[64] = 0 sentinel
    __shared__ float zp_s[NW][NT];
    __shared__ float z_s[NT];
    __shared__ float p_s[64];

    const int tid  = threadIdx.x;
    const int wave = tid >> 6;
    const int lane = tid & 63;
    const int seg  = blockIdx.x;
    const int b    = seg >> 7;
    const int start = seg_starts[seg];
    const int len   = seg_lens[seg];

    if (tid < LL) tok_s[tid] = tokens[b * SS + start + tid];
    __syncthreads();

    // ---- u in registers (coalesced global read, no LDS round-trip) ----
    float uu[NC];
    {
        const float* up = u_ws + (size_t)seg * DD;
        uu[0] = up[lane];
        uu[1] = up[lane + 64];
        uu[2] = up[lane + 128];
        uu[3] = up[lane + 192];
        uu[4] = (lane < 44) ? up[lane + 256] : 0.f;
    }

    // ---- pure-load phase: 65 unconditional clamped loads ----
    float rr[NJ][NC];
    #pragma unroll
    for (int j = 0; j < NJ; ++j) {
        const int l  = wave + j * NW;
        const int lc = (l < len) ? l : (len - 1);
        const float* row = emb + (size_t)tok_s[lc] * DD;
        rr[j][0] = row[lane];
        rr[j][1] = row[lane + 64];
        rr[j][2] = row[lane + 128];
        rr[j][3] = row[lane + 192];
        rr[j][4] = (lane < 44) ? row[lane + 256] : 0.f;
    }

    // ---- esc dots: 13 independent shuffle-reduce chains ----
    #pragma unroll
    for (int j = 0; j < NJ; ++j) {
        const int l = wave + j * NW;
        float dot = rr[j][0] * uu[0] + rr[j][1] * uu[1] + rr[j][2] * uu[2]
                  + rr[j][3] * uu[3] + rr[j][4] * uu[4];
        dot = wave_sum(dot);
        if (lane == 0 && l < len) a_s[l] = dot;
    }
    __syncthreads();

    // ---- softmax over rows (wave 0); sentinel by wave 4 ----
    if (wave == 0) {
        const float v  = (lane < len) ? a_s[lane] : -INFINITY;
        const float mx = wave_max(v);
        const float e  = (lane < len) ? __expf(v - mx) : 0.f;
        const float sm = wave_sum(e);
        a_s[lane] = e / sm;            // zeros for padded lanes
    }
    if (tid == NT - 1) a_s[LL] = 0.f;
    __syncthreads();

    // ---- z from register rows (alpha = 0 kills clamped pad rows) ----
    {
        float zacc[NC] = {0.f, 0.f, 0.f, 0.f, 0.f};
        #pragma unroll
        for (int j = 0; j < NJ; ++j) {
            const int l = wave + j * NW;
            const float a = a_s[l];    // LDS broadcast
            #pragma unroll
            for (int c = 0; c < NC; ++c) zacc[c] += a * rr[j][c];
        }
        #pragma unroll
        for (int c = 0; c < NC; ++c) zp_s[wave][lane + 64 * c] = zacc[c];
    }
    __syncthreads();

    if (tid < DD) {
        const float zv = zp_s[0][tid] + zp_s[1][tid] + zp_s[2][tid] + zp_s[3][tid] + zp_s[4][tid];
        z_s[tid] = zv;
        out_z[(size_t)seg * DD + tid] = zv;
    }
    __syncthreads();

    // ---- topic scores: wave-per-k (10 per wave) ----
    for (int k = wave; k < KK; k += NW) {
        const float* wr = W_w + (size_t)k * DD;
        float d0 = wr[lane] * z_s[lane] + wr[lane + 64] * z_s[lane + 64]
                 + wr[lane + 128] * z_s[lane + 128] + wr[lane + 192] * z_s[lane + 192];
        if (lane < 44) d0 += wr[lane + 256] * z_s[lane + 256];
        d0 = wave_sum(d0);
        if (lane == 0) p_s[k] = d0;
    }
    __syncthreads();

    // ---- softmax over k (wave 0), write p ----
    if (wave == 0) {
        const float v  = (lane < KK) ? p_s[lane] : -INFINITY;
        const float mx = wave_max(v);
        const float e  = (lane < KK) ? __expf(v - mx) : 0.f;
        const float sm = wave_sum(e);
        if (lane < KK) {
            const float p = e / sm;
            p_s[lane] = p;
            out_p[(size_t)seg * KK + lane] = p;
        }
    }
    __syncthreads();

    // ---- r[d] = sum_k p[k] * T_w[d,k] ----
    if (tid < DD) {
        const float* trow = T_w + (size_t)tid * KK;
        float acc = 0.f;
        #pragma unroll
        for (int k = 0; k < KK; ++k) acc += p_s[k] * trow[k];
        out_r[(size_t)seg * DD + tid] = acc;
    }
}

extern "C" void kernel_launch(void* const* d_in, const int* in_sizes, int n_in,
                              void* d_out, int out_size, void* d_ws, size_t ws_size,
                              hipStream_t stream) {
    const float* emb        = (const float*)d_in[0];
    const float* M_w        = (const float*)d_in[1];
    const float* W_w        = (const float*)d_in[2];
    const float* T_w        = (const float*)d_in[3];
    const int*   tokens     = (const int*)d_in[4];
    const int*   seg_starts = (const int*)d_in[5];
    const int*   seg_lens   = (const int*)d_in[6];

    float* out   = (float*)d_out;
    float* out_y = out;                                    // [NSEG*D]
    float* out_z = out + (size_t)NSEG * DD;                // [NSEG*D]
    float* out_p = out + (size_t)2 * NSEG * DD;            // [NSEG*K]
    float* out_r = out + (size_t)2 * NSEG * DD + (size_t)NSEG * KK;

    float* u_ws = (float*)d_ws;                            // [NSEG*D] = 4.9 MB

    hipLaunchKernelGGL(k_y, dim3(NSEG), dim3(NT), 0, stream,
                       emb, tokens, seg_starts, seg_lens, out_y);
    hipLaunchKernelGGL(k_u, dim3(NSEG / TM), dim3(NT), 0, stream,
                       out_y, M_w, u_ws);
    hipLaunchKernelGGL(k_rest, dim3(NSEG), dim3(NT), 0, stream,
                       emb, W_w, T_w, tokens, seg_starts, seg_lens,
                       u_ws, out_z, out_p, out_r);
}